// Round 4
// baseline (195.945 us; speedup 1.0000x reference)
//
#include <hip/hip_runtime.h>
#include <math.h>

// MultiHeadAttention_3728031613617 — bf16-MFMA, register-fragment pipeline (v4).
// B=8, S=2048, D=512, head=64, heads=8 (identical heads => compute once).
// out = (softmax(0.1*(xWq)(xWk)^T) @ (xWv)) @ dr, dr[j,o] = sum_h dense[h*64+j,o]
// v4: flash loads Q/K/V MFMA fragments DIRECTLY from global (L2-resident) into
// registers — no LDS staging, no ds_write->ds_read turnarounds except the
// mandatory P transpose. 512-thr blocks (8-wave K-split), 16 waves/CU.

typedef __bf16 bf16;
typedef __bf16 bf16x4v __attribute__((ext_vector_type(4)));
typedef __bf16 bf16x8v __attribute__((ext_vector_type(8)));
typedef float f32x4 __attribute__((ext_vector_type(4)));

namespace {
constexpr int kS = 2048;
constexpr int kD = 512;
constexpr int kRows = 16384;  // 8 * 2048
}

#define MFMA16(a, b, c) __builtin_amdgcn_mfma_f32_16x16x32_bf16((a), (b), (c), 0, 0, 0)

// ---------------------------------------------------------------------------
// Kernel 0: prep. wtg[mat][n=64][k=512] = (bf16)W[mat][k][n]   (98304 elems)
//           drt[o=512][j=64] = (bf16) sum_h dense[h*64+j, o]   (32768 elems)
// ---------------------------------------------------------------------------
__global__ __launch_bounds__(256) void prep_kernel(const float* __restrict__ w,
                                                   const float* __restrict__ dense,
                                                   bf16* __restrict__ wtg,
                                                   bf16* __restrict__ drt) {
  int idx = blockIdx.x * 256 + threadIdx.x;  // < 131072
  if (idx < 98304) {
    int mat = idx >> 15, rem = idx & 32767;
    int n = rem >> 9, k = rem & 511;
    wtg[idx] = (bf16)w[mat * 32768 + k * 64 + n];
  } else {
    int e = idx - 98304;  // < 32768
    int o = e >> 6, j = e & 63;
    float s = 0.f;
#pragma unroll
    for (int h = 0; h < 8; ++h) s += dense[(size_t)(h * 64 + j) * kD + o];
    drt[e] = (bf16)s;  // [o][j]
  }
}

// ---------------------------------------------------------------------------
// Kernel 1: fused QKV projection (x read ONCE). grid 256, block 256.
// wq[row][64], wk[row][64], wvt[64][16384] (transposed; written COALESCED via
// an LDS transpose — round-3's 2B/32KB-stride scatter was a write-allocate
// disaster).
// ---------------------------------------------------------------------------
__global__ __launch_bounds__(256) void proj_kernel(const float* __restrict__ x,
                                                   const bf16* __restrict__ wtg,
                                                   bf16* __restrict__ wq,
                                                   bf16* __restrict__ wk,
                                                   bf16* __restrict__ wvt) {
  const int bt = blockIdx.x;
  const int tid = threadIdx.x;
  const int w = tid >> 6, tx = tid & 15, quad = (tid >> 4) & 3;
  const int row0 = bt * 64;

  __shared__ bf16 Xs[64 * 72];       // 64 rows x 64 k, stride 72 (pad)
  __shared__ bf16 Wts[3 * 64 * 72];  // 3 mats x 64 n x 64 k, stride 72

  f32x4 acc[3][4];
#pragma unroll
  for (int m = 0; m < 3; ++m)
#pragma unroll
    for (int nt = 0; nt < 4; ++nt) acc[m][nt] = (f32x4){0.f, 0.f, 0.f, 0.f};

  for (int k0 = 0; k0 < kD; k0 += 64) {
    __syncthreads();
#pragma unroll
    for (int p = 0; p < 4; ++p) {
      int i4 = tid + p * 256;  // 1024 groups of 4
      int r = i4 >> 4, c4 = (i4 & 15) * 4;
      float4 f = *(const float4*)&x[(size_t)(row0 + r) * kD + k0 + c4];
      bf16x4v h = {(bf16)f.x, (bf16)f.y, (bf16)f.z, (bf16)f.w};
      *(bf16x4v*)&Xs[r * 72 + c4] = h;
    }
#pragma unroll
    for (int p = 0; p < 6; ++p) {
      int cc = tid + p * 256;  // 1536 chunks of 8 bf16
      int mat = cc >> 9, rem = cc & 511;
      int n = rem >> 3, c8 = (rem & 7) * 8;
      *(uint4*)&Wts[(mat * 64 + n) * 72 + c8] =
          *(const uint4*)&wtg[(size_t)mat * 32768 + (size_t)n * 512 + k0 + c8];
    }
    __syncthreads();
#pragma unroll
    for (int s = 0; s < 2; ++s) {
      bf16x8v a = *(bf16x8v*)&Xs[(w * 16 + tx) * 72 + s * 32 + quad * 8];
#pragma unroll
      for (int m = 0; m < 3; ++m)
#pragma unroll
        for (int nt = 0; nt < 4; ++nt) {
          bf16x8v bfr =
              *(bf16x8v*)&Wts[(m * 64 + nt * 16 + tx) * 72 + s * 32 + quad * 8];
          acc[m][nt] = MFMA16(a, bfr, acc[m][nt]);
        }
    }
  }

  // epilogue: C/D row = quad*4+r, col = nt*16+tx
#pragma unroll
  for (int nt = 0; nt < 4; ++nt)
#pragma unroll
    for (int r = 0; r < 4; ++r) {
      int row_g = row0 + w * 16 + quad * 4 + r;
      int col = nt * 16 + tx;
      wq[(size_t)row_g * 64 + col] = (bf16)acc[0][nt][r];
      wk[(size_t)row_g * 64 + col] = (bf16)acc[1][nt][r];
    }
  // V: transpose in LDS (reuse Xs), then coalesced 128B-per-row stores
  __syncthreads();
  bf16* Vt = Xs;  // 64 cols x 64 local-rows, stride 72
#pragma unroll
  for (int nt = 0; nt < 4; ++nt)
#pragma unroll
    for (int r = 0; r < 4; ++r)
      Vt[(nt * 16 + tx) * 72 + (w * 16 + quad * 4 + r)] = (bf16)acc[2][nt][r];
  __syncthreads();
#pragma unroll
  for (int p = 0; p < 2; ++p) {
    int c = tid + p * 256;  // 512 chunks of 8 bf16: 64 v-rows x 128B
    int v = c >> 3, seg = c & 7;
    *(uint4*)&wvt[(size_t)v * kRows + row0 + seg * 8] =
        *(uint4*)&Vt[v * 72 + seg * 8];
  }
}

// ---------------------------------------------------------------------------
// Kernel 2: flash attention + fused dense epilogue, register fragments.
// grid 512: b = bid&7 (XCD affinity), qb = bid>>3 (32 Q-rows). Block 512 = 8
// waves; wave w owns key tiles (t*8+w)*32, t<8. Q/K/V frags loaded straight
// from global (all L2-resident); only P round-trips LDS (padded, conflict-free).
// Cross-wave combine via LDS f32 atomics; dense epilogue writes out directly.
// ---------------------------------------------------------------------------
__global__ __launch_bounds__(512, 4) void flash_kernel(
    const bf16* __restrict__ wq, const bf16* __restrict__ wk,
    const bf16* __restrict__ wvt, const bf16* __restrict__ drt,
    float* __restrict__ out) {
  const int bid = blockIdx.x;
  const int b = bid & 7, qb = bid >> 3;
  const int q0 = qb * 32;
  const int tid = threadIdx.x;
  const int w = tid >> 6, tx = tid & 15, quad = (tid >> 4) & 3;

  __shared__ __align__(16) bf16 Psw_all[8 * 32 * 40];  // 20480 B
  __shared__ float Osh[32 * 66];                       // 8448 B (padded)
  __shared__ float Lsh[32];
  __shared__ __align__(16) bf16 vob[32 * 72];          // 4608 B
  bf16* Psw = Psw_all + w * (32 * 40);

  // zero combine buffers (ordered by the post-loop barrier)
  for (int i = tid; i < 32 * 66; i += 512) Osh[i] = 0.f;
  if (tid < 32) Lsh[tid] = 0.f;

  const bf16* wqb = wq + (size_t)(b * kS) * 64;
  const bf16* wkb = wk + (size_t)(b * kS) * 64;
  const bf16* wvb = wvt + b * kS;

  // Q fragments: direct global load, loop-invariant
  bf16x8v aq[2][2];
#pragma unroll
  for (int rt = 0; rt < 2; ++rt)
#pragma unroll
    for (int s = 0; s < 2; ++s)
      aq[rt][s] = *(const bf16x8v*)&wqb[(size_t)(q0 + rt * 16 + tx) * 64 +
                                        s * 32 + quad * 8];

  f32x4 oacc[2][4];
#pragma unroll
  for (int rt = 0; rt < 2; ++rt)
#pragma unroll
    for (int nt = 0; nt < 4; ++nt) oacc[rt][nt] = (f32x4){0.f, 0.f, 0.f, 0.f};
  float lsum[2][4] = {};

  for (int t = 0; t < 8; ++t) {
    const int k0 = (t * 8 + w) * 32;  // this wave's 32-key tile
    // K fragments (4 independent global loads)
    bf16x8v kb[2][2];
#pragma unroll
    for (int nt = 0; nt < 2; ++nt)
#pragma unroll
      for (int s = 0; s < 2; ++s)
        kb[nt][s] = *(const bf16x8v*)&wkb[(size_t)(k0 + nt * 16 + tx) * 64 +
                                          s * 32 + quad * 8];
    // V fragments (issued early; consumed after the P transpose)
    bf16x8v vb[4];
#pragma unroll
    for (int nt = 0; nt < 4; ++nt)
      vb[nt] = *(const bf16x8v*)&wvb[(size_t)(nt * 16 + tx) * kRows + k0 +
                                     quad * 8];

    // QK^T + no-max softmax numerator + P store (C-layout -> A-layout)
#pragma unroll
    for (int nt = 0; nt < 2; ++nt) {
      f32x4 z0 = (f32x4){0.f, 0.f, 0.f, 0.f};
      f32x4 z1 = (f32x4){0.f, 0.f, 0.f, 0.f};
      z0 = MFMA16(aq[0][0], kb[nt][0], z0);
      z0 = MFMA16(aq[0][1], kb[nt][1], z0);
      z1 = MFMA16(aq[1][0], kb[nt][0], z1);
      z1 = MFMA16(aq[1][1], kb[nt][1], z1);
#pragma unroll
      for (int r = 0; r < 4; ++r) {
        float p0 = __expf(z0[r] * 0.1f);
        float p1 = __expf(z1[r] * 0.1f);
        lsum[0][r] += p0;
        lsum[1][r] += p1;
        Psw[(quad * 4 + r) * 40 + nt * 16 + tx] = (bf16)p0;
        Psw[(16 + quad * 4 + r) * 40 + nt * 16 + tx] = (bf16)p1;
      }
    }
    // PV
    bf16x8v pa0 = *(bf16x8v*)&Psw[tx * 40 + quad * 8];
    bf16x8v pa1 = *(bf16x8v*)&Psw[(16 + tx) * 40 + quad * 8];
#pragma unroll
    for (int nt = 0; nt < 4; ++nt) {
      oacc[0][nt] = MFMA16(pa0, vb[nt], oacc[0][nt]);
      oacc[1][nt] = MFMA16(pa1, vb[nt], oacc[1][nt]);
    }
  }

  // ---- cross-wave combine via LDS atomics ----
  __syncthreads();
#pragma unroll
  for (int rt = 0; rt < 2; ++rt)
#pragma unroll
    for (int nt = 0; nt < 4; ++nt)
#pragma unroll
      for (int r = 0; r < 4; ++r)
        atomicAdd(&Osh[(rt * 16 + quad * 4 + r) * 66 + nt * 16 + tx],
                  oacc[rt][nt][r]);
#pragma unroll
  for (int rt = 0; rt < 2; ++rt)
#pragma unroll
    for (int r = 0; r < 4; ++r) {
      float v = lsum[rt][r];
#pragma unroll
      for (int m = 1; m < 16; m <<= 1) v += __shfl_xor(v, m, 64);
      if (tx == 0) atomicAdd(&Lsh[rt * 16 + quad * 4 + r], v);
    }
  __syncthreads();
  for (int e = tid; e < 2048; e += 512) {
    int row = e >> 6, col = e & 63;
    vob[row * 72 + col] = (bf16)(Osh[row * 66 + col] / Lsh[row]);
  }
  __syncthreads();

  // ---- fused dense epilogue: out[32 x 512] = vob[32 x 64] @ drt^T ----
  bf16x8v av[2][2];
#pragma unroll
  for (int rt = 0; rt < 2; ++rt)
#pragma unroll
    for (int s = 0; s < 2; ++s)
      av[rt][s] = *(bf16x8v*)&vob[(rt * 16 + tx) * 72 + s * 32 + quad * 8];

#pragma unroll
  for (int i = 0; i < 4; ++i) {
    const int ct = w * 4 + i;  // 16-col output tile
    bf16x8v bd0 = *(const bf16x8v*)&drt[(size_t)(ct * 16 + tx) * 64 + quad * 8];
    bf16x8v bd1 =
        *(const bf16x8v*)&drt[(size_t)(ct * 16 + tx) * 64 + 32 + quad * 8];
#pragma unroll
    for (int rt = 0; rt < 2; ++rt) {
      f32x4 z = (f32x4){0.f, 0.f, 0.f, 0.f};
      z = MFMA16(av[rt][0], bd0, z);
      z = MFMA16(av[rt][1], bd1, z);
#pragma unroll
      for (int r = 0; r < 4; ++r)
        out[(size_t)(b * kS + q0 + rt * 16 + quad * 4 + r) * kD + ct * 16 +
            tx] = z[r];
    }
  }
}

extern "C" void kernel_launch(void* const* d_in, const int* in_sizes, int n_in,
                              void* d_out, int out_size, void* d_ws,
                              size_t ws_size, hipStream_t stream) {
  const float* x = (const float*)d_in[0];      // [8,2048,512]
  const float* w = (const float*)d_in[1];      // [3,512,64]
  const float* dense = (const float*)d_in[2];  // [512,512]
  float* out = (float*)d_out;                  // [8,2048,512] fp32

  // workspace (~6.6 MB)
  bf16* wq = (bf16*)d_ws;                // 1,048,576
  bf16* wk = wq + (size_t)kRows * 64;    // 1,048,576
  bf16* wvt = wk + (size_t)kRows * 64;   // 1,048,576  [64][16384]
  bf16* wtg = wvt + (size_t)kRows * 64;  // 98,304     [3][64][512]
  bf16* drt = wtg + 98304;               // 32,768     [512][64]

  prep_kernel<<<512, 256, 0, stream>>>(w, dense, wtg, drt);
  proj_kernel<<<256, 256, 0, stream>>>(x, wtg, wq, wk, wvt);
  flash_kernel<<<512, 512, 0, stream>>>(wq, wk, wvt, drt, out);
}